// Round 19
// baseline (197.039 us; speedup 1.0000x reference)
//
#include <hip/hip_runtime.h>
#include <hip/hip_bf16.h>
#include <math.h>

// Fused MHA block: proj(Q,K,V) -> masked softmax attention -> out proj + residual -> LayerNorm
// Round 19: gemm_qkv re-tiled 128x128 -> 64x128 (BK=32): grid 768 -> 1536 blocks
// (6 blocks/CU, LDS 24KB, ~24 waves/CU vs 12). Same template, parameter change only.
// Attn (round-14 512-thr version, proven 74us), cvt_all, gemm_out32, LN unchanged.

#define D_MODEL 1024
#define NHEADS  16
#define DHEAD   64
#define BATCH   2
#define SEQ     2048
#define MROWS   (BATCH * SEQ)   // 4096
#define SCLF    0.18033688f     // 0.125 * log2(e), folded into Q projection

typedef __attribute__((ext_vector_type(8)))  short bf16x8;
typedef __attribute__((ext_vector_type(4)))  float f32x4;
typedef __attribute__((ext_vector_type(16))) float f32x16;

__device__ inline unsigned short f2bf(float f) {
    unsigned int u = __builtin_bit_cast(unsigned int, f);
    unsigned int r = (u + 0x7FFFu + ((u >> 16) & 1u)) >> 16;   // RNE
    return (unsigned short)r;
}

__device__ inline unsigned cvtpk_bf16(float lo, float hi2) {
    unsigned r;
    asm("v_cvt_pk_bf16_f32 %0, %1, %2" : "=v"(r) : "v"(lo), "v"(hi2));
    return r;
}

// global -> LDS direct copy, 16B per lane. lbase must be wave-uniform.
__device__ inline void gload16(const unsigned short* g, unsigned short* lbase, int lane) {
#if __has_builtin(__builtin_amdgcn_global_load_lds)
    __builtin_amdgcn_global_load_lds(
        (const __attribute__((address_space(1))) unsigned int*)g,
        (__attribute__((address_space(3))) unsigned int*)lbase, 16, 0, 0);
#else
    *(bf16x8*)(lbase + lane * 8) = *(const bf16x8*)g;
#endif
}

// ---------------------------------------------------------------------------
// Parallel mask dtype probe. flags[0]: any word not in {0,1};
// flags[1]: any word not in {0, 0x3F800000}. flags pre-zeroed via memset.
// ---------------------------------------------------------------------------
__global__ __launch_bounds__(256) void detect_mask_par(
    const unsigned int* __restrict__ m, int nwords, int* __restrict__ flags)
{
    const int i = blockIdx.x * 256 + threadIdx.x;
    int a = 0, b = 0;
    if (i < nwords) {
        const unsigned int w = m[i];
        a = (w != 0u && w != 1u);
        b = (w != 0u && w != 0x3F800000u);
    }
    const int wa = (int)__any(a);
    const int wb = (int)__any(b);
    if ((threadIdx.x & 63) == 0) {
        if (wa) atomicOr(&flags[0], 1);
        if (wb) atomicOr(&flags[1], 1);
    }
}

// ---------------------------------------------------------------------------
// Merged convert kernel. z=0..2: Q/K/V fp32 -> bf16 (8 elems/thread).
// z=3..6: weight transpose-convert W fp32 [K][N] -> Wt bf16 [N][K].
// z=7: ballot mask pack (lane i reads element i of a 64-key row; __ballot IS
//      the packed word). flags from detect_mask_par (earlier dispatch).
// ---------------------------------------------------------------------------
__global__ __launch_bounds__(256) void cvt_all(
    const float* __restrict__ Q, const float* __restrict__ K,
    const float* __restrict__ V,
    const float* __restrict__ w0, const float* __restrict__ w1,
    const float* __restrict__ w2, const float* __restrict__ w3,
    unsigned short* __restrict__ Qb, unsigned short* __restrict__ Kb,
    unsigned short* __restrict__ Vb,
    unsigned short* __restrict__ t0, unsigned short* __restrict__ t1,
    unsigned short* __restrict__ t2, unsigned short* __restrict__ t3,
    const void* __restrict__ mask, const int* __restrict__ flags,
    unsigned long long* __restrict__ mbits, int nwords)
{
    __shared__ float tile[64][65];
    const int z = blockIdx.z;
    if (z < 3) {
        const float* s = (z == 0) ? Q : (z == 1) ? K : V;
        unsigned short* d = (z == 0) ? Qb : (z == 1) ? Kb : Vb;
        const int i = blockIdx.x * 256 + threadIdx.x;
        float4 a = ((const float4*)s)[i * 2];
        float4 b = ((const float4*)s)[i * 2 + 1];
        unsigned u0 = cvtpk_bf16(a.x, a.y);
        unsigned u1 = cvtpk_bf16(a.z, a.w);
        unsigned u2 = cvtpk_bf16(b.x, b.y);
        unsigned u3 = cvtpk_bf16(b.z, b.w);
        ((int4*)d)[i] = make_int4((int)u0, (int)u1, (int)u2, (int)u3);
    } else if (z < 7) {
        if (blockIdx.x >= 256) return;
        const int wz = z - 3;
        const float* W = (wz == 0) ? w0 : (wz == 1) ? w1 : (wz == 2) ? w2 : w3;
        unsigned short* T = (wz == 0) ? t0 : (wz == 1) ? t1 : (wz == 2) ? t2 : t3;
        const int n0 = (blockIdx.x & 15) * 64;
        const int k0 = (blockIdx.x >> 4) * 64;
        const int t  = threadIdx.x;
        const int r  = t >> 4;
        const int c4 = (t & 15) * 4;
        #pragma unroll
        for (int u = 0; u < 4; ++u) {
            float4 v = *(const float4*)(W + (size_t)(k0 + r + u * 16) * D_MODEL + n0 + c4);
            tile[r + u * 16][c4 + 0] = v.x;
            tile[r + u * 16][c4 + 1] = v.y;
            tile[r + u * 16][c4 + 2] = v.z;
            tile[r + u * 16][c4 + 3] = v.w;
        }
        __syncthreads();
        #pragma unroll
        for (int u = 0; u < 4; ++u) {
            const int nr = r + u * 16;
            ushort4 o;
            o.x = f2bf(tile[c4 + 0][nr]);
            o.y = f2bf(tile[c4 + 1][nr]);
            o.z = f2bf(tile[c4 + 2][nr]);
            o.w = f2bf(tile[c4 + 3][nr]);
            *(ushort4*)(T + (size_t)(n0 + nr) * D_MODEL + k0 + c4) = o;
        }
    } else {
        const int lane   = threadIdx.x & 63;
        const int wv     = blockIdx.x * 4 + (threadIdx.x >> 6);
        const int nwaves = gridDim.x * 4;
        const int mf = (flags[0] == 0) ? 0 : (flags[1] == 0) ? 1 : 2;
        for (int w = wv; w < nwords; w += nwaves) {
            bool bit;
            if (mf == 0)      bit = ((const unsigned int*)mask)[(size_t)w * 64 + lane] != 0u;
            else if (mf == 1) bit = ((const float*)mask)[(size_t)w * 64 + lane] != 0.f;
            else              bit = ((const unsigned char*)mask)[(size_t)w * 64 + lane] != 0;
            const unsigned long long bb = __ballot(bit);
            if (lane == 0) mbits[w] = bb;
        }
    }
}

// ---------------------------------------------------------------------------
// Merged Q/K/V projection GEMM: 64x128 tile (M x N), BK=32, 256 threads
// (4 waves, 2x2 of 32x64 each), dbuf LDS 24KB -> 6 blocks/CU on a 1536-block
// grid. m-major: x = m-tile, x%8 = XCD shares the A-panel.
// z=0: Q (scaled by SCLF); z=1: K; z=2: V transposed vt[b][h][d][tok].
// ---------------------------------------------------------------------------
#define BKQ 32
__global__ __launch_bounds__(256, 1) void gemm_qkv(
    const unsigned short* __restrict__ A0, const unsigned short* __restrict__ A1,
    const unsigned short* __restrict__ A2,
    const unsigned short* __restrict__ B0, const unsigned short* __restrict__ B1,
    const unsigned short* __restrict__ B2,
    const float* __restrict__ bias0, const float* __restrict__ bias1,
    const float* __restrict__ bias2,
    unsigned short* __restrict__ C0, unsigned short* __restrict__ C1,
    unsigned short* __restrict__ C2)
{
    const int z = blockIdx.z;
    const unsigned short* A  = (z == 0) ? A0 : (z == 1) ? A1 : A2;
    const unsigned short* Bt = (z == 0) ? B0 : (z == 1) ? B1 : B2;
    const float* bias        = (z == 0) ? bias0 : (z == 1) ? bias1 : bias2;
    unsigned short* C        = (z == 0) ? C0 : (z == 1) ? C1 : C2;
    const int K = D_MODEL, N = D_MODEL;

    __shared__ unsigned short As[2][64 * BKQ];    // 8 KB
    __shared__ unsigned short Bs[2][128 * BKQ];   // 16 KB
    const int tid  = threadIdx.x;
    const int w    = tid >> 6;
    const int lane = tid & 63;
    const int lo   = lane & 15;
    const int hi   = lane >> 4;
    const int wm   = (w >> 1) * 32;      // 2 wave-rows of 32
    const int wn   = (w & 1) * 64;       // 2 wave-cols of 64
    const int m0   = blockIdx.x * 64;    // m-major
    const int n0   = blockIdx.y * 128;

    const unsigned short* Ab = A  + (size_t)m0 * K;
    const unsigned short* Bb = Bt + (size_t)n0 * K;

    f32x4 acc[2][4];
    #pragma unroll
    for (int i = 0; i < 2; ++i)
        #pragma unroll
        for (int j = 0; j < 4; ++j) acc[i][j] = (f32x4){0.f, 0.f, 0.f, 0.f};

    const int NT = K / BKQ;   // 32
    auto stage = [&](int buf, int t) {
        const int k0 = t * BKQ;
        // A: 64 rows x 4 chunks = 256 -> 1 chunk/thread
        gload16(Ab + (size_t)(tid >> 2) * K + k0 + (tid & 3) * 8,
                &As[buf][(w * 64) * 8], lane);
        // B: 128 rows x 4 chunks = 512 -> 2 chunks/thread
        #pragma unroll
        for (int i = 0; i < 2; ++i) {
            const int c = i * 256 + tid;
            gload16(Bb + (size_t)(c >> 2) * K + k0 + (c & 3) * 8,
                    &Bs[buf][(i * 256 + w * 64) * 8], lane);
        }
    };

    stage(0, 0);
    __syncthreads();
    int cur = 0;
    for (int t = 0; t < NT; ++t) {
        if (t + 1 < NT) stage(cur ^ 1, t + 1);
        bf16x8 af[2], bfr[4];
        #pragma unroll
        for (int f = 0; f < 2; ++f)
            af[f] = *(const bf16x8*)&As[cur][(wm + f * 16 + lo) * BKQ + hi * 8];
        #pragma unroll
        for (int f = 0; f < 4; ++f)
            bfr[f] = *(const bf16x8*)&Bs[cur][(wn + f * 16 + lo) * BKQ + hi * 8];
        #pragma unroll
        for (int fm = 0; fm < 2; ++fm)
            #pragma unroll
            for (int fn = 0; fn < 4; ++fn)
                acc[fm][fn] = __builtin_amdgcn_mfma_f32_16x16x32_bf16(
                    af[fm], bfr[fn], acc[fm][fn], 0, 0, 0);
        __syncthreads();
        cur ^= 1;
    }

    #pragma unroll
    for (int fm = 0; fm < 2; ++fm) {
        const int row = m0 + wm + fm * 16 + hi * 4;
        #pragma unroll
        for (int fn = 0; fn < 4; ++fn) {
            const int col = n0 + wn + fn * 16 + lo;
            const float bv = bias[col];
            #pragma unroll
            for (int r = 0; r < 4; ++r) {
                float o = acc[fm][fn][r] + bv;
                if (z == 0) o *= SCLF;            // fold softmax scale into Q
                if (z < 2)
                    C[(size_t)(row + r) * N + col] = f2bf(o);
                else
                    C[(size_t)((row + r) >> 11) * 2097152
                      + (size_t)col * 2048 + ((row + r) & 2047)] = f2bf(o);
            }
        }
    }
}

// ---------------------------------------------------------------------------
// Out-projection GEMM: 64x64 tile, BK=32, m-major grid (1024 blocks = 4/CU),
// LDS 16KB. fp32 out + bias + residual.
// ---------------------------------------------------------------------------
__global__ __launch_bounds__(256) void gemm_out32(
    const unsigned short* __restrict__ A, const unsigned short* __restrict__ Bt,
    const float* __restrict__ bias, const float* __restrict__ resid,
    float* __restrict__ C)
{
    const int K = D_MODEL, N = D_MODEL;
    __shared__ unsigned short As[2][64 * 32];
    __shared__ unsigned short Bs[2][64 * 32];
    const int tid  = threadIdx.x;
    const int w    = tid >> 6;
    const int lane = tid & 63;
    const int lo   = lane & 15;
    const int hi   = lane >> 4;
    const int wm   = (w >> 1) * 32;
    const int wn   = (w & 1) * 32;
    const int m0   = blockIdx.x * 64;    // m-major: x%8 = XCD shares A-panel
    const int n0   = blockIdx.y * 64;

    const unsigned short* Ab = A  + (size_t)m0 * K;
    const unsigned short* Bb = Bt + (size_t)n0 * K;

    f32x4 acc[2][2];
    #pragma unroll
    for (int i = 0; i < 2; ++i)
        #pragma unroll
        for (int j = 0; j < 2; ++j) acc[i][j] = (f32x4){0.f, 0.f, 0.f, 0.f};

    const int NT = K / 32;   // 32
    auto stage = [&](int buf, int t) {
        const int k0 = t * 32;
        gload16(Ab + (size_t)(tid >> 2) * K + k0 + (tid & 3) * 8,
                &As[buf][(w * 64) * 8], lane);
        gload16(Bb + (size_t)(tid >> 2) * K + k0 + (tid & 3) * 8,
                &Bs[buf][(w * 64) * 8], lane);
    };

    stage(0, 0);
    __syncthreads();
    int cur = 0;
    for (int t = 0; t < NT; ++t) {
        if (t + 1 < NT) stage(cur ^ 1, t + 1);
        bf16x8 af[2], bfr[2];
        #pragma unroll
        for (int f = 0; f < 2; ++f) {
            af[f]  = *(const bf16x8*)&As[cur][(wm + f * 16 + lo) * 32 + hi * 8];
            bfr[f] = *(const bf16x8*)&Bs[cur][(wn + f * 16 + lo) * 32 + hi * 8];
        }
        #pragma unroll
        for (int fm = 0; fm < 2; ++fm)
            #pragma unroll
            for (int fn = 0; fn < 2; ++fn)
                acc[fm][fn] = __builtin_amdgcn_mfma_f32_16x16x32_bf16(
                    af[fm], bfr[fn], acc[fm][fn], 0, 0, 0);
        __syncthreads();
        cur ^= 1;
    }

    #pragma unroll
    for (int fm = 0; fm < 2; ++fm) {
        const int row = m0 + wm + fm * 16 + hi * 4;
        #pragma unroll
        for (int fn = 0; fn < 2; ++fn) {
            const int col = n0 + wn + fn * 16 + lo;
            const float bv = bias[col];
            #pragma unroll
            for (int r = 0; r < 4; ++r)
                C[(size_t)(row + r) * N + col] =
                    acc[fm][fn][r] + bv + resid[(size_t)(row + r) * N + col];
        }
    }
}

// ---------------------------------------------------------------------------
// Swapped-QK^T 32x32 MFMA flash attention, static-zero-max softmax, KVBLK=32.
// l computed via ones-MFMA. V tile [64d][32key] with parity rotate swizzle
// slot=(c+(d>>1))&3. Grid h-major; 8 waves = 2 k-groups x 4 q-waves,
// 32 tiles of 32 keys per group. (round-14 version, proven ~74us)
// ---------------------------------------------------------------------------
__global__ __launch_bounds__(512, 2) void attn_mfma32(
    const unsigned short* __restrict__ qb, const unsigned short* __restrict__ kbm,
    const unsigned short* __restrict__ vt,
    const unsigned long long* __restrict__ mbits, unsigned short* __restrict__ ctx)
{
    // [0,16K): K staging (group g at g*8KB); [16K,32K): V staging.
    // combine: ovals stride-33 at [0,33792) + lvals at [33792, 34304).
    __shared__ __align__(16) unsigned char smem[34304];
    const int tid  = threadIdx.x;
    const int w8   = tid >> 6;
    const int g    = w8 >> 2;        // k-group (keys [g*1024, g*1024+1024))
    const int wq   = w8 & 3;         // q-wave within group
    const int lane = tid & 63;
    const int l31  = lane & 31;
    const int hi   = lane >> 5;
    const int h    = blockIdx.x;     // h-major for K/V L2 locality
    const int q0   = blockIdx.y * 128;
    const int b    = blockIdx.z;

    unsigned short* KsG = (unsigned short*)smem + (size_t)g * 4096;            // [2][2048]
    unsigned short* VsG = (unsigned short*)(smem + 16384) + (size_t)g * 4096;  // [2][2048]

    const size_t qkbase = (size_t)b * SEQ * D_MODEL + (size_t)h * DHEAD;
    const size_t vtbase = ((size_t)b * D_MODEL + h * DHEAD) * SEQ;

    const int qtok = q0 + wq * 32 + l31;
    bf16x8 qA[4];
    #pragma unroll
    for (int s = 0; s < 4; ++s)
        qA[s] = *(const bf16x8*)(qb + qkbase + (size_t)qtok * D_MODEL + s * 16 + hi * 8);

    // ones B-operand for l-sum MFMA (bf16 1.0 = 0x3F80)
    const int4 ones_i = make_int4(0x3F803F80, 0x3F803F80, 0x3F803F80, 0x3F803F80);
    const bf16x8 ones = __builtin_bit_cast(bf16x8, ones_i);

    f32x16 o0 = {}, o1 = {}, accl = {};

    const unsigned long long* mrow = mbits + ((size_t)b * SEQ + qtok) * (SEQ / 64);

    // K staging: tile rows 32 x 8 chunks; wave covers rows [wq*8, wq*8+8)
    const int krow = wq * 8 + (lane >> 3);
    const int kc   = lane & 7;
    const int kswz = kc ^ (krow & 7);
    // V staging: tile rows(d) 64 x 4 chunks; wave covers d rows [wq*16, wq*16+16)
    const int vrow = wq * 16 + (lane >> 2);
    const int vsrc = ((lane & 3) - (vrow >> 1)) & 3;   // parity rotate swizzle source

    const unsigned short* kl = kbm + qkbase + (size_t)(g * 1024 + krow) * D_MODEL + kswz * 8;
    const unsigned short* vl = vt + vtbase + (size_t)vrow * SEQ + g * 1024 + vsrc * 8;
    const int kldb = (wq * 8) * 64;    // wave-uniform LDS base (shorts)
    const int vldb = (wq * 16) * 32;

    auto stage = [&](int buf) {
        gload16(kl, &KsG[buf * 2048 + kldb], lane);
        gload16(vl, &VsG[buf * 2048 + vldb], lane);
        kl += (size_t)32 * D_MODEL;
        vl += 32;
    };

    stage(0);
    unsigned long long mw64 = mrow[g * 16];     // covers tiles 0,1
    __syncthreads();
    int cur = 0;

    for (int t = 0; t < 32; ++t) {
        if (t + 1 < 32) stage(cur ^ 1);
        const unsigned int mw = (unsigned int)(mw64 >> (32 * (t & 1) + 4 * hi));
        if ((t & 1) && t + 1 < 32) mw64 = mrow[g * 16 + ((t + 1) >> 1)];  // prefetch

        // ---- QK^T (pre-scaled Q): S^T[key 0..31][q] ----
        f32x16 st = {};
        __builtin_amdgcn_s_setprio(1);
        #pragma unroll
        for (int s = 0; s < 4; ++s) {
            bf16x8 kf = *(const bf16x8*)&KsG[cur * 2048 + l31 * 64 + ((2 * s + hi) ^ (l31 & 7)) * 8];
            st = __builtin_amdgcn_mfma_f32_32x32x16_bf16(kf, qA[s], st, 0, 0, 0);
        }
        __builtin_amdgcn_s_setprio(0);

        // ---- mask + exp2 (no max subtraction; exp2(-1e9)=+0) ----
        #pragma unroll
        for (int r = 0; r < 16; ++r) {
            const int klo = (r & 3) + 8 * (r >> 2);
            const float x = ((mw >> klo) & 1u) ? -1e9f : st[r];
            st[r] = exp2f(x);
        }

        // ---- P -> bf16 A-frags (T12): pa[0]=keys 0..15, pa[1]=keys 16..31 ----
        bf16x8 pa[2];
        #pragma unroll
        for (int s = 0; s < 2; ++s) {
            const int base = s * 8;
            unsigned av  = cvtpk_bf16(st[base + 0], st[base + 1]);
            unsigned bv2 = cvtpk_bf16(st[base + 4], st[base + 5]);
            unsigned cv  = cvtpk_bf16(st[base + 2], st[base + 3]);
            unsigned dv  = cvtpk_bf16(st[base + 6], st[base + 7]);
            asm("v_permlane32_swap_b32 %0, %1" : "+v"(av), "+v"(bv2));
            asm("v_permlane32_swap_b32 %0, %1" : "+v"(cv), "+v"(dv));
            int4 pk = make_int4((int)av, (int)cv, (int)bv2, (int)dv);
            pa[s] = __builtin_bit_cast(bf16x8, pk);
        }

        // ---- PV + l-sum: o0 (d=l31), o1 (d=32+l31), accl = P @ 1 ----
        __builtin_amdgcn_s_setprio(1);
        #pragma unroll
        for (int s = 0; s < 2; ++s) {
            const int slot = ((2 * s + hi) + (l31 >> 1)) & 3;   // same for d and d+32
            bf16x8 vf0 = *(const bf16x8*)&VsG[cur * 2048 + l31 * 32 + slot * 8];
            o0 = __builtin_amdgcn_mfma_f32_32x32x16_bf16(pa[s], vf0, o0, 0, 0, 0);
            bf16x8 vf1 = *(const bf16x8*)&VsG[cur * 2048 + (32 + l31) * 32 + slot * 8];
            o1 = __builtin_amdgcn_mfma_f32_32x32x16_bf16(pa[s], vf1, o1, 0, 0, 0);
            accl = __builtin_amdgcn_mfma_f32_32x32x16_bf16(pa[s], ones, accl, 0, 0, 0);
        }
        __builtin_amdgcn_s_setprio(0);
        __syncthreads();
        cur ^= 1;
    }

    // ---- combine the two k-groups; accl[r] = l for q=qloc(r,hi), any n ----
    __syncthreads();
    float* comb  = (float*)smem;                   // [wq][lane][33], stride 33
    float* lvals = (float*)(smem + 33792);         // [wq][32 q]
    if (g == 1) {
        float* p = comb + (size_t)(wq * 64 + lane) * 33;
        #pragma unroll
        for (int r = 0; r < 16; ++r) { p[r] = o0[r]; p[16 + r] = o1[r]; }
        if (l31 == 0) {
            #pragma unroll
            for (int r = 0; r < 16; ++r)
                lvals[wq * 32 + (r & 3) + 8 * (r >> 2) + 4 * hi] = accl[r];
        }
    }
    __syncthreads();
    if (g == 0) {
        const float* p = comb + (size_t)(wq * 64 + lane) * 33;
        #pragma unroll
        for (int r = 0; r < 16; ++r) {
            const int qloc = (r & 3) + 8 * (r >> 2) + 4 * hi;
            const float inv = 1.f / (accl[r] + lvals[wq * 32 + qloc]);
            unsigned short* dst = ctx + qkbase + (size_t)(q0 + wq * 32 + qloc) * D_MODEL;
            dst[l31]      = f2bf((o0[r] + p[r]) * inv);
            dst[32 + l31] = f2bf((o1[r] + p[16 + r]) * inv);
        }
    }
}

// ---------------------------------------------------------------------------
// LayerNorm over last dim (1024). One block per row.
// ---------------------------------------------------------------------------
__global__ __launch_bounds__(256) void layernorm1024(
    const float* __restrict__ x, const float* __restrict__ gamma,
    const float* __restrict__ beta, float* __restrict__ out)
{
    const int row = blockIdx.x;
    const int tid = threadIdx.x;
    const float* xr = x + (size_t)row * D_MODEL;
    float4 v = *(const float4*)(xr + (tid << 2));
    float s = v.x + v.y + v.z + v.w;
    float q = v.x * v.x + v.y * v.y + v.z * v.z + v.w * v.w;
    #pragma unroll
    for (int off = 1; off < 64; off <<= 1) {
        s += __shfl_xor(s, off, 64);
        q += __shfl_xor(q, off, 64);
    }
    __shared__ float sw[4], qw_[4];
    const int wid = tid >> 6;
    if ((tid & 63) == 0) { sw[wid] = s; qw_[wid] = q; }
    __syncthreads();
    s = sw[0] + sw[1] + sw[2] + sw[3];
    q = qw_[0] + qw_[1] + qw_[2] + qw_[3];
    const float mu  = s * (1.f / D_MODEL);
    const float var = q * (1.f / D_MODEL) - mu * mu;
    const float a = var + 1e-5f;
    float inv = rsqrtf(a);
    inv = inv * (1.5f - 0.5f * a * inv * inv);
    float4 gg = *(const float4*)(gamma + (tid << 2));
    float4 bt = *(const float4*)(beta + (tid << 2));
    float4 o;
    o.x = (v.x - mu) * inv * gg.x + bt.x;
    o.y = (v.y - mu) * inv * gg.y + bt.y;
    o.z = (v.z - mu) * inv * gg.z + bt.z;
    o.w = (v.w - mu) * inv * gg.w + bt.w;
    *(float4*)(out + (size_t)row * D_MODEL + (tid << 2)) = o;
}

// ---------------------------------------------------------------------------
extern "C" void kernel_launch(void* const* d_in, const int* in_sizes, int n_in,
                              void* d_out, int out_size, void* d_ws, size_t ws_size,
                              hipStream_t stream)
{
    const float* Q    = (const float*)d_in[0];
    const float* K    = (const float*)d_in[1];
    const float* V    = (const float*)d_in[2];
    const void*  mask = d_in[3];
    const float* Wq   = (const float*)d_in[4];
    const float* bq   = (const float*)d_in[5];
    const float* Wk   = (const float*)d_in[6];
    const float* bk   = (const float*)d_in[7];
    const float* Wv   = (const float*)d_in[8];
    const float* bv   = (const float*)d_in[9];
    const float* Wo   = (const float*)d_in[10];
    const float* bo   = (const float*)d_in[11];
    const float* gam  = (const float*)d_in[12];
    const float* bet  = (const float*)d_in[13];
    float* out = (float*)d_out;

    const size_t NE = (size_t)MROWS * D_MODEL;           // 4,194,304 elems
    const size_t WE = (size_t)D_MODEL * D_MODEL;
    const size_t NMW = (size_t)BATCH * SEQ * (SEQ / 64); // 131072 mask words
    unsigned short* Qbf = (unsigned short*)d_ws;         // reused as ctxb
    unsigned short* Kbf = Qbf + NE;                      // Kbf+Vbf reused as outp
    unsigned short* Vbf = Kbf + NE;
    unsigned short* qb  = Vbf + NE;
    unsigned short* kb  = qb + NE;
    unsigned short* vt  = kb + NE;                       // [b][h][d][tok]
    unsigned short* Wt0 = vt + NE;
    unsigned short* Wt1 = Wt0 + WE;
    unsigned short* Wt2 = Wt1 + WE;
    unsigned short* Wt3 = Wt2 + WE;
    unsigned long long* mbits = (unsigned long long*)(Wt3 + WE);
    int* mflags = (int*)(mbits + NMW);
    unsigned short* ctxb = Qbf;
    float* outp = (float*)Kbf;
    if (ws_size < 6 * NE * 2 + 4 * WE * 2 + NMW * 8 + 64) return;

    hipMemsetAsync(mflags, 0, 2 * sizeof(int), stream);
    detect_mask_par<<<256, 256, 0, stream>>>((const unsigned int*)mask, 65536, mflags);

    cvt_all<<<dim3(2048, 1, 8), 256, 0, stream>>>(Q, K, V, Wq, Wk, Wv, Wo,
                                                  Qbf, Kbf, Vbf, Wt0, Wt1, Wt2, Wt3,
                                                  mask, mflags, mbits, (int)NMW);

    gemm_qkv<<<dim3(64, 8, 3), 256, 0, stream>>>(Qbf, Kbf, Vbf, Wt0, Wt1, Wt2,
                                                 bq, bk, bv, qb, kb, vt);

    dim3 ag(NHEADS, SEQ / 128, BATCH);     // h-major: (16, 16, 2), 512 threads
    attn_mfma32<<<ag, 512, 0, stream>>>(qb, kb, vt, mbits, ctxb);

    gemm_out32<<<dim3(64, 16), 256, 0, stream>>>(ctxb, Wt3, bo, Q, outp);

    layernorm1024<<<MROWS, 256, 0, stream>>>(outp, gam, bet, out);
}

// Round 20
// 179.963 us; speedup vs baseline: 1.0949x; 1.0949x over previous
//
#include <hip/hip_runtime.h>
#include <hip/hip_bf16.h>
#include <math.h>

// Fused MHA block: proj(Q,K,V) -> masked softmax attention -> out proj + residual -> LayerNorm
// Round 20: pure revert to round-18 (proven 180.4us; best of 20 rounds). Round-19's
// 64x128 gemm_qkv tile doubled B traffic and regressed +17us. Final configuration:
//  - gemm_qkv: 128x128 tile, BK=32, m-major grid (768 blocks, A-panel XCD reuse)
//  - attn: swapped-QK^T 32x32 MFMA, 512 thr, KVBLK=32, static-zero-max softmax,
//    l via ones-MFMA, h-major grid, parity-rotate V swizzle
//  - gemm_out32: 64x64/BK32; cvt_all merged (QKV cvt + 4x weight transpose + mask pack)

#define D_MODEL 1024
#define NHEADS  16
#define DHEAD   64
#define BATCH   2
#define SEQ     2048
#define MROWS   (BATCH * SEQ)   // 4096
#define SCLF    0.18033688f     // 0.125 * log2(e), folded into Q projection

typedef __attribute__((ext_vector_type(8)))  short bf16x8;
typedef __attribute__((ext_vector_type(4)))  float f32x4;
typedef __attribute__((ext_vector_type(16))) float f32x16;

__device__ inline unsigned short f2bf(float f) {
    unsigned int u = __builtin_bit_cast(unsigned int, f);
    unsigned int r = (u + 0x7FFFu + ((u >> 16) & 1u)) >> 16;   // RNE
    return (unsigned short)r;
}

__device__ inline unsigned cvtpk_bf16(float lo, float hi2) {
    unsigned r;
    asm("v_cvt_pk_bf16_f32 %0, %1, %2" : "=v"(r) : "v"(lo), "v"(hi2));
    return r;
}

// global -> LDS direct copy, 16B per lane. lbase must be wave-uniform.
__device__ inline void gload16(const unsigned short* g, unsigned short* lbase, int lane) {
#if __has_builtin(__builtin_amdgcn_global_load_lds)
    __builtin_amdgcn_global_load_lds(
        (const __attribute__((address_space(1))) unsigned int*)g,
        (__attribute__((address_space(3))) unsigned int*)lbase, 16, 0, 0);
#else
    *(bf16x8*)(lbase + lane * 8) = *(const bf16x8*)g;
#endif
}

// ---------------------------------------------------------------------------
// Parallel mask dtype probe. flags[0]: any word not in {0,1};
// flags[1]: any word not in {0, 0x3F800000}. flags pre-zeroed via memset.
// ---------------------------------------------------------------------------
__global__ __launch_bounds__(256) void detect_mask_par(
    const unsigned int* __restrict__ m, int nwords, int* __restrict__ flags)
{
    const int i = blockIdx.x * 256 + threadIdx.x;
    int a = 0, b = 0;
    if (i < nwords) {
        const unsigned int w = m[i];
        a = (w != 0u && w != 1u);
        b = (w != 0u && w != 0x3F800000u);
    }
    const int wa = (int)__any(a);
    const int wb = (int)__any(b);
    if ((threadIdx.x & 63) == 0) {
        if (wa) atomicOr(&flags[0], 1);
        if (wb) atomicOr(&flags[1], 1);
    }
}

// ---------------------------------------------------------------------------
// Merged convert kernel. z=0..2: Q/K/V fp32 -> bf16 (8 elems/thread).
// z=3..6: weight transpose-convert W fp32 [K][N] -> Wt bf16 [N][K].
// z=7: ballot mask pack (lane i reads element i of a 64-key row; __ballot IS
//      the packed word). flags from detect_mask_par (earlier dispatch).
// ---------------------------------------------------------------------------
__global__ __launch_bounds__(256) void cvt_all(
    const float* __restrict__ Q, const float* __restrict__ K,
    const float* __restrict__ V,
    const float* __restrict__ w0, const float* __restrict__ w1,
    const float* __restrict__ w2, const float* __restrict__ w3,
    unsigned short* __restrict__ Qb, unsigned short* __restrict__ Kb,
    unsigned short* __restrict__ Vb,
    unsigned short* __restrict__ t0, unsigned short* __restrict__ t1,
    unsigned short* __restrict__ t2, unsigned short* __restrict__ t3,
    const void* __restrict__ mask, const int* __restrict__ flags,
    unsigned long long* __restrict__ mbits, int nwords)
{
    __shared__ float tile[64][65];
    const int z = blockIdx.z;
    if (z < 3) {
        const float* s = (z == 0) ? Q : (z == 1) ? K : V;
        unsigned short* d = (z == 0) ? Qb : (z == 1) ? Kb : Vb;
        const int i = blockIdx.x * 256 + threadIdx.x;
        float4 a = ((const float4*)s)[i * 2];
        float4 b = ((const float4*)s)[i * 2 + 1];
        unsigned u0 = cvtpk_bf16(a.x, a.y);
        unsigned u1 = cvtpk_bf16(a.z, a.w);
        unsigned u2 = cvtpk_bf16(b.x, b.y);
        unsigned u3 = cvtpk_bf16(b.z, b.w);
        ((int4*)d)[i] = make_int4((int)u0, (int)u1, (int)u2, (int)u3);
    } else if (z < 7) {
        if (blockIdx.x >= 256) return;
        const int wz = z - 3;
        const float* W = (wz == 0) ? w0 : (wz == 1) ? w1 : (wz == 2) ? w2 : w3;
        unsigned short* T = (wz == 0) ? t0 : (wz == 1) ? t1 : (wz == 2) ? t2 : t3;
        const int n0 = (blockIdx.x & 15) * 64;
        const int k0 = (blockIdx.x >> 4) * 64;
        const int t  = threadIdx.x;
        const int r  = t >> 4;
        const int c4 = (t & 15) * 4;
        #pragma unroll
        for (int u = 0; u < 4; ++u) {
            float4 v = *(const float4*)(W + (size_t)(k0 + r + u * 16) * D_MODEL + n0 + c4);
            tile[r + u * 16][c4 + 0] = v.x;
            tile[r + u * 16][c4 + 1] = v.y;
            tile[r + u * 16][c4 + 2] = v.z;
            tile[r + u * 16][c4 + 3] = v.w;
        }
        __syncthreads();
        #pragma unroll
        for (int u = 0; u < 4; ++u) {
            const int nr = r + u * 16;
            ushort4 o;
            o.x = f2bf(tile[c4 + 0][nr]);
            o.y = f2bf(tile[c4 + 1][nr]);
            o.z = f2bf(tile[c4 + 2][nr]);
            o.w = f2bf(tile[c4 + 3][nr]);
            *(ushort4*)(T + (size_t)(n0 + nr) * D_MODEL + k0 + c4) = o;
        }
    } else {
        const int lane   = threadIdx.x & 63;
        const int wv     = blockIdx.x * 4 + (threadIdx.x >> 6);
        const int nwaves = gridDim.x * 4;
        const int mf = (flags[0] == 0) ? 0 : (flags[1] == 0) ? 1 : 2;
        for (int w = wv; w < nwords; w += nwaves) {
            bool bit;
            if (mf == 0)      bit = ((const unsigned int*)mask)[(size_t)w * 64 + lane] != 0u;
            else if (mf == 1) bit = ((const float*)mask)[(size_t)w * 64 + lane] != 0.f;
            else              bit = ((const unsigned char*)mask)[(size_t)w * 64 + lane] != 0;
            const unsigned long long bb = __ballot(bit);
            if (lane == 0) mbits[w] = bb;
        }
    }
}

// ---------------------------------------------------------------------------
// Merged Q/K/V projection GEMM, bf16, global_load_lds staging, BK=32.
// 128x128 tile, m-major grid (768 blocks; x%8 = XCD shares the A-panel).
// z=0: Q (scaled by SCLF); z=1: K; z=2: V transposed vt[b][h][d][tok].
// ---------------------------------------------------------------------------
#define BKQ 32
__global__ __launch_bounds__(256, 1) void gemm_qkv(
    const unsigned short* __restrict__ A0, const unsigned short* __restrict__ A1,
    const unsigned short* __restrict__ A2,
    const unsigned short* __restrict__ B0, const unsigned short* __restrict__ B1,
    const unsigned short* __restrict__ B2,
    const float* __restrict__ bias0, const float* __restrict__ bias1,
    const float* __restrict__ bias2,
    unsigned short* __restrict__ C0, unsigned short* __restrict__ C1,
    unsigned short* __restrict__ C2)
{
    const int z = blockIdx.z;
    const unsigned short* A  = (z == 0) ? A0 : (z == 1) ? A1 : A2;
    const unsigned short* Bt = (z == 0) ? B0 : (z == 1) ? B1 : B2;
    const float* bias        = (z == 0) ? bias0 : (z == 1) ? bias1 : bias2;
    unsigned short* C        = (z == 0) ? C0 : (z == 1) ? C1 : C2;
    const int K = D_MODEL, N = D_MODEL;

    __shared__ unsigned short As[2][128 * BKQ];
    __shared__ unsigned short Bs[2][128 * BKQ];
    const int tid  = threadIdx.x;
    const int w    = tid >> 6;
    const int lane = tid & 63;
    const int lo   = lane & 15;
    const int hi   = lane >> 4;
    const int wm   = (w >> 1) * 64;
    const int wn   = (w & 1) * 64;
    const int m0   = blockIdx.x * 128;   // m-major
    const int n0   = blockIdx.y * 128;

    const unsigned short* Ab = A  + (size_t)m0 * K;
    const unsigned short* Bb = Bt + (size_t)n0 * K;

    f32x4 acc[4][4];
    #pragma unroll
    for (int i = 0; i < 4; ++i)
        #pragma unroll
        for (int j = 0; j < 4; ++j) acc[i][j] = (f32x4){0.f, 0.f, 0.f, 0.f};

    const int NT = K / BKQ;   // 32
    auto stage = [&](int buf, int t) {
        const int k0 = t * BKQ;
        #pragma unroll
        for (int i = 0; i < 2; ++i) {
            const int c = i * 256 + tid;
            gload16(Ab + (size_t)(c >> 2) * K + k0 + (c & 3) * 8,
                    &As[buf][(i * 256 + w * 64) * 8], lane);
        }
        #pragma unroll
        for (int i = 0; i < 2; ++i) {
            const int c = i * 256 + tid;
            gload16(Bb + (size_t)(c >> 2) * K + k0 + (c & 3) * 8,
                    &Bs[buf][(i * 256 + w * 64) * 8], lane);
        }
    };

    stage(0, 0);
    __syncthreads();
    int cur = 0;
    for (int t = 0; t < NT; ++t) {
        if (t + 1 < NT) stage(cur ^ 1, t + 1);
        bf16x8 af[4], bfr[4];
        #pragma unroll
        for (int f = 0; f < 4; ++f) {
            af[f]  = *(const bf16x8*)&As[cur][(wm + f * 16 + lo) * BKQ + hi * 8];
            bfr[f] = *(const bf16x8*)&Bs[cur][(wn + f * 16 + lo) * BKQ + hi * 8];
        }
        #pragma unroll
        for (int fm = 0; fm < 4; ++fm)
            #pragma unroll
            for (int fn = 0; fn < 4; ++fn)
                acc[fm][fn] = __builtin_amdgcn_mfma_f32_16x16x32_bf16(
                    af[fm], bfr[fn], acc[fm][fn], 0, 0, 0);
        __syncthreads();
        cur ^= 1;
    }

    #pragma unroll
    for (int fm = 0; fm < 4; ++fm) {
        const int row = m0 + wm + fm * 16 + hi * 4;
        #pragma unroll
        for (int fn = 0; fn < 4; ++fn) {
            const int col = n0 + wn + fn * 16 + lo;
            const float bv = bias[col];
            #pragma unroll
            for (int r = 0; r < 4; ++r) {
                float o = acc[fm][fn][r] + bv;
                if (z == 0) o *= SCLF;            // fold softmax scale into Q
                if (z < 2)
                    C[(size_t)(row + r) * N + col] = f2bf(o);
                else
                    C[(size_t)((row + r) >> 11) * 2097152
                      + (size_t)col * 2048 + ((row + r) & 2047)] = f2bf(o);
            }
        }
    }
}

// ---------------------------------------------------------------------------
// Out-projection GEMM: 64x64 tile, BK=32, m-major grid (1024 blocks = 4/CU),
// LDS 16KB. fp32 out + bias + residual.
// ---------------------------------------------------------------------------
__global__ __launch_bounds__(256) void gemm_out32(
    const unsigned short* __restrict__ A, const unsigned short* __restrict__ Bt,
    const float* __restrict__ bias, const float* __restrict__ resid,
    float* __restrict__ C)
{
    const int K = D_MODEL, N = D_MODEL;
    __shared__ unsigned short As[2][64 * 32];
    __shared__ unsigned short Bs[2][64 * 32];
    const int tid  = threadIdx.x;
    const int w    = tid >> 6;
    const int lane = tid & 63;
    const int lo   = lane & 15;
    const int hi   = lane >> 4;
    const int wm   = (w >> 1) * 32;
    const int wn   = (w & 1) * 32;
    const int m0   = blockIdx.x * 64;    // m-major: x%8 = XCD shares A-panel
    const int n0   = blockIdx.y * 64;

    const unsigned short* Ab = A  + (size_t)m0 * K;
    const unsigned short* Bb = Bt + (size_t)n0 * K;

    f32x4 acc[2][2];
    #pragma unroll
    for (int i = 0; i < 2; ++i)
        #pragma unroll
        for (int j = 0; j < 2; ++j) acc[i][j] = (f32x4){0.f, 0.f, 0.f, 0.f};

    const int NT = K / 32;   // 32
    auto stage = [&](int buf, int t) {
        const int k0 = t * 32;
        gload16(Ab + (size_t)(tid >> 2) * K + k0 + (tid & 3) * 8,
                &As[buf][(w * 64) * 8], lane);
        gload16(Bb + (size_t)(tid >> 2) * K + k0 + (tid & 3) * 8,
                &Bs[buf][(w * 64) * 8], lane);
    };

    stage(0, 0);
    __syncthreads();
    int cur = 0;
    for (int t = 0; t < NT; ++t) {
        if (t + 1 < NT) stage(cur ^ 1, t + 1);
        bf16x8 af[2], bfr[2];
        #pragma unroll
        for (int f = 0; f < 2; ++f) {
            af[f]  = *(const bf16x8*)&As[cur][(wm + f * 16 + lo) * 32 + hi * 8];
            bfr[f] = *(const bf16x8*)&Bs[cur][(wn + f * 16 + lo) * 32 + hi * 8];
        }
        #pragma unroll
        for (int fm = 0; fm < 2; ++fm)
            #pragma unroll
            for (int fn = 0; fn < 2; ++fn)
                acc[fm][fn] = __builtin_amdgcn_mfma_f32_16x16x32_bf16(
                    af[fm], bfr[fn], acc[fm][fn], 0, 0, 0);
        __syncthreads();
        cur ^= 1;
    }

    #pragma unroll
    for (int fm = 0; fm < 2; ++fm) {
        const int row = m0 + wm + fm * 16 + hi * 4;
        #pragma unroll
        for (int fn = 0; fn < 2; ++fn) {
            const int col = n0 + wn + fn * 16 + lo;
            const float bv = bias[col];
            #pragma unroll
            for (int r = 0; r < 4; ++r)
                C[(size_t)(row + r) * N + col] =
                    acc[fm][fn][r] + bv + resid[(size_t)(row + r) * N + col];
        }
    }
}

// ---------------------------------------------------------------------------
// Swapped-QK^T 32x32 MFMA flash attention, static-zero-max softmax, KVBLK=32.
// l computed via ones-MFMA. V tile [64d][32key] with parity rotate swizzle
// slot=(c+(d>>1))&3. Grid h-major; 8 waves = 2 k-groups x 4 q-waves,
// 32 tiles of 32 keys per group. (round-14 version, proven ~74us)
// ---------------------------------------------------------------------------
__global__ __launch_bounds__(512, 2) void attn_mfma32(
    const unsigned short* __restrict__ qb, const unsigned short* __restrict__ kbm,
    const unsigned short* __restrict__ vt,
    const unsigned long long* __restrict__ mbits, unsigned short* __restrict__ ctx)
{
    // [0,16K): K staging (group g at g*8KB); [16K,32K): V staging.
    // combine: ovals stride-33 at [0,33792) + lvals at [33792, 34304).
    __shared__ __align__(16) unsigned char smem[34304];
    const int tid  = threadIdx.x;
    const int w8   = tid >> 6;
    const int g    = w8 >> 2;        // k-group (keys [g*1024, g*1024+1024))
    const int wq   = w8 & 3;         // q-wave within group
    const int lane = tid & 63;
    const int l31  = lane & 31;
    const int hi   = lane >> 5;
    const int h    = blockIdx.x;     // h-major for K/V L2 locality
    const int q0   = blockIdx.y * 128;
    const int b    = blockIdx.z;

    unsigned short* KsG = (unsigned short*)smem + (size_t)g * 4096;            // [2][2048]
    unsigned short* VsG = (unsigned short*)(smem + 16384) + (size_t)g * 4096;  // [2][2048]

    const size_t qkbase = (size_t)b * SEQ * D_MODEL + (size_t)h * DHEAD;
    const size_t vtbase = ((size_t)b * D_MODEL + h * DHEAD) * SEQ;

    const int qtok = q0 + wq * 32 + l31;
    bf16x8 qA[4];
    #pragma unroll
    for (int s = 0; s < 4; ++s)
        qA[s] = *(const bf16x8*)(qb + qkbase + (size_t)qtok * D_MODEL + s * 16 + hi * 8);

    // ones B-operand for l-sum MFMA (bf16 1.0 = 0x3F80)
    const int4 ones_i = make_int4(0x3F803F80, 0x3F803F80, 0x3F803F80, 0x3F803F80);
    const bf16x8 ones = __builtin_bit_cast(bf16x8, ones_i);

    f32x16 o0 = {}, o1 = {}, accl = {};

    const unsigned long long* mrow = mbits + ((size_t)b * SEQ + qtok) * (SEQ / 64);

    // K staging: tile rows 32 x 8 chunks; wave covers rows [wq*8, wq*8+8)
    const int krow = wq * 8 + (lane >> 3);
    const int kc   = lane & 7;
    const int kswz = kc ^ (krow & 7);
    // V staging: tile rows(d) 64 x 4 chunks; wave covers d rows [wq*16, wq*16+16)
    const int vrow = wq * 16 + (lane >> 2);
    const int vsrc = ((lane & 3) - (vrow >> 1)) & 3;   // parity rotate swizzle source

    const unsigned short* kl = kbm + qkbase + (size_t)(g * 1024 + krow) * D_MODEL + kswz * 8;
    const unsigned short* vl = vt + vtbase + (size_t)vrow * SEQ + g * 1024 + vsrc * 8;
    const int kldb = (wq * 8) * 64;    // wave-uniform LDS base (shorts)
    const int vldb = (wq * 16) * 32;

    auto stage = [&](int buf) {
        gload16(kl, &KsG[buf * 2048 + kldb], lane);
        gload16(vl, &VsG[buf * 2048 + vldb], lane);
        kl += (size_t)32 * D_MODEL;
        vl += 32;
    };

    stage(0);
    unsigned long long mw64 = mrow[g * 16];     // covers tiles 0,1
    __syncthreads();
    int cur = 0;

    for (int t = 0; t < 32; ++t) {
        if (t + 1 < 32) stage(cur ^ 1);
        const unsigned int mw = (unsigned int)(mw64 >> (32 * (t & 1) + 4 * hi));
        if ((t & 1) && t + 1 < 32) mw64 = mrow[g * 16 + ((t + 1) >> 1)];  // prefetch

        // ---- QK^T (pre-scaled Q): S^T[key 0..31][q] ----
        f32x16 st = {};
        __builtin_amdgcn_s_setprio(1);
        #pragma unroll
        for (int s = 0; s < 4; ++s) {
            bf16x8 kf = *(const bf16x8*)&KsG[cur * 2048 + l31 * 64 + ((2 * s + hi) ^ (l31 & 7)) * 8];
            st = __builtin_amdgcn_mfma_f32_32x32x16_bf16(kf, qA[s], st, 0, 0, 0);
        }
        __builtin_amdgcn_s_setprio(0);

        // ---- mask + exp2 (no max subtraction; exp2(-1e9)=+0) ----
        #pragma unroll
        for (int r = 0; r < 16; ++r) {
            const int klo = (r & 3) + 8 * (r >> 2);
            const float x = ((mw >> klo) & 1u) ? -1e9f : st[r];
            st[r] = exp2f(x);
        }

        // ---- P -> bf16 A-frags (T12): pa[0]=keys 0..15, pa[1]=keys 16..31 ----
        bf16x8 pa[2];
        #pragma unroll
        for (int s = 0; s < 2; ++s) {
            const int base = s * 8;
            unsigned av  = cvtpk_bf16(st[base + 0], st[base + 1]);
            unsigned bv2 = cvtpk_bf16(st[base + 4], st[base + 5]);
            unsigned cv  = cvtpk_bf16(st[base + 2], st[base + 3]);
            unsigned dv  = cvtpk_bf16(st[base + 6], st[base + 7]);
            asm("v_permlane32_swap_b32 %0, %1" : "+v"(av), "+v"(bv2));
            asm("v_permlane32_swap_b32 %0, %1" : "+v"(cv), "+v"(dv));
            int4 pk = make_int4((int)av, (int)cv, (int)bv2, (int)dv);
            pa[s] = __builtin_bit_cast(bf16x8, pk);
        }

        // ---- PV + l-sum: o0 (d=l31), o1 (d=32+l31), accl = P @ 1 ----
        __builtin_amdgcn_s_setprio(1);
        #pragma unroll
        for (int s = 0; s < 2; ++s) {
            const int slot = ((2 * s + hi) + (l31 >> 1)) & 3;   // same for d and d+32
            bf16x8 vf0 = *(const bf16x8*)&VsG[cur * 2048 + l31 * 32 + slot * 8];
            o0 = __builtin_amdgcn_mfma_f32_32x32x16_bf16(pa[s], vf0, o0, 0, 0, 0);
            bf16x8 vf1 = *(const bf16x8*)&VsG[cur * 2048 + (32 + l31) * 32 + slot * 8];
            o1 = __builtin_amdgcn_mfma_f32_32x32x16_bf16(pa[s], vf1, o1, 0, 0, 0);
            accl = __builtin_amdgcn_mfma_f32_32x32x16_bf16(pa[s], ones, accl, 0, 0, 0);
        }
        __builtin_amdgcn_s_setprio(0);
        __syncthreads();
        cur ^= 1;
    }

    // ---- combine the two k-groups; accl[r] = l for q=qloc(r,hi), any n ----
    __syncthreads();
    float* comb  = (float*)smem;                   // [wq][lane][33], stride 33
    float* lvals = (float*)(smem + 33792);         // [wq][32 q]
    if (g == 1) {
        float* p = comb + (size_t)(wq * 64 + lane) * 33;
        #pragma unroll
        for (int r = 0; r < 16; ++r) { p[r] = o0[r]; p[16 + r] = o1[r]; }
        if (l31 == 0) {
            #pragma unroll
            for (int r = 0; r < 16; ++r)
                lvals[wq * 32 + (r & 3) + 8 * (r >> 2) + 4 * hi] = accl[r];
        }
    }
    __syncthreads();
    if (g == 0) {
        const float* p = comb + (size_t)(wq * 64 + lane) * 33;
        #pragma unroll
        for (int r = 0; r < 16; ++r) {
            const int qloc = (r & 3) + 8 * (r >> 2) + 4 * hi;
            const float inv = 1.f / (accl[r] + lvals[wq * 32 + qloc]);
            unsigned short* dst = ctx + qkbase + (size_t)(q0 + wq * 32 + qloc) * D_MODEL;
            dst[l31]      = f2bf((o0[r] + p[r]) * inv);
            dst[32 + l31] = f2bf((o1[r] + p[16 + r]) * inv);
        }
    }
}

// ---------------------------------------------------------------------------
// LayerNorm over last dim (1024). One block per row.
// ---------------------------------------------------------------------------
__global__ __launch_bounds__(256) void layernorm1024(
    const float* __restrict__ x, const float* __restrict__ gamma,
    const float* __restrict__ beta, float* __restrict__ out)
{
    const int row = blockIdx.x;
    const int tid = threadIdx.x;
    const float* xr = x + (size_t)row * D_MODEL;
    float4 v = *(const float4*)(xr + (tid << 2));
    float s = v.x + v.y + v.z + v.w;
    float q = v.x * v.x + v.y * v.y + v.z * v.z + v.w * v.w;
    #pragma unroll
    for (int off = 1; off < 64; off <<= 1) {
        s += __shfl_xor(s, off, 64);
        q += __shfl_xor(q, off, 64);
    }
    __shared__ float sw[4], qw_[4];
    const int wid = tid >> 6;
    if ((tid & 63) == 0) { sw[wid] = s; qw_[wid] = q; }
    __syncthreads();
    s = sw[0] + sw[1] + sw[2] + sw[3];
    q = qw_[0] + qw_[1] + qw_[2] + qw_[3];
    const float mu  = s * (1.f / D_MODEL);
    const float var = q * (1.f / D_MODEL) - mu * mu;
    const float a = var + 1e-5f;
    float inv = rsqrtf(a);
    inv = inv * (1.5f - 0.5f * a * inv * inv);
    float4 gg = *(const float4*)(gamma + (tid << 2));
    float4 bt = *(const float4*)(beta + (tid << 2));
    float4 o;
    o.x = (v.x - mu) * inv * gg.x + bt.x;
    o.y = (v.y - mu) * inv * gg.y + bt.y;
    o.z = (v.z - mu) * inv * gg.z + bt.z;
    o.w = (v.w - mu) * inv * gg.w + bt.w;
    *(float4*)(out + (size_t)row * D_MODEL + (tid << 2)) = o;
}

// ---------------------------------------------------------------------------
extern "C" void kernel_launch(void* const* d_in, const int* in_sizes, int n_in,
                              void* d_out, int out_size, void* d_ws, size_t ws_size,
                              hipStream_t stream)
{
    const float* Q    = (const float*)d_in[0];
    const float* K    = (const float*)d_in[1];
    const float* V    = (const float*)d_in[2];
    const void*  mask = d_in[3];
    const float* Wq   = (const float*)d_in[4];
    const float* bq   = (const float*)d_in[5];
    const float* Wk   = (const float*)d_in[6];
    const float* bk   = (const float*)d_in[7];
    const float* Wv   = (const float*)d_in[8];
    const float* bv   = (const float*)d_in[9];
    const float* Wo   = (const float*)d_in[10];
    const float* bo   = (const float*)d_in[11];
    const float* gam  = (const float*)d_in[12];
    const float* bet  = (const float*)d_in[13];
    float* out = (float*)d_out;

    const size_t NE = (size_t)MROWS * D_MODEL;           // 4,194,304 elems
    const size_t WE = (size_t)D_MODEL * D_MODEL;
    const size_t NMW = (size_t)BATCH * SEQ * (SEQ / 64); // 131072 mask words
    unsigned short* Qbf = (unsigned short*)d_ws;         // reused as ctxb
    unsigned short* Kbf = Qbf + NE;                      // Kbf+Vbf reused as outp
    unsigned short* Vbf = Kbf + NE;
    unsigned short* qb  = Vbf + NE;
    unsigned short* kb  = qb + NE;
    unsigned short* vt  = kb + NE;                       // [b][h][d][tok]
    unsigned short* Wt0 = vt + NE;
    unsigned short* Wt1 = Wt0 + WE;
    unsigned short* Wt2 = Wt1 + WE;
    unsigned short* Wt3 = Wt2 + WE;
    unsigned long long* mbits = (unsigned long long*)(Wt3 + WE);
    int* mflags = (int*)(mbits + NMW);
    unsigned short* ctxb = Qbf;
    float* outp = (float*)Kbf;
    if (ws_size < 6 * NE * 2 + 4 * WE * 2 + NMW * 8 + 64) return;

    hipMemsetAsync(mflags, 0, 2 * sizeof(int), stream);
    detect_mask_par<<<256, 256, 0, stream>>>((const unsigned int*)mask, 65536, mflags);

    cvt_all<<<dim3(2048, 1, 8), 256, 0, stream>>>(Q, K, V, Wq, Wk, Wv, Wo,
                                                  Qbf, Kbf, Vbf, Wt0, Wt1, Wt2, Wt3,
                                                  mask, mflags, mbits, (int)NMW);

    gemm_qkv<<<dim3(32, 8, 3), 256, 0, stream>>>(Qbf, Kbf, Vbf, Wt0, Wt1, Wt2,
                                                 bq, bk, bv, qb, kb, vt);

    dim3 ag(NHEADS, SEQ / 128, BATCH);     // h-major: (16, 16, 2), 512 threads
    attn_mfma32<<<ag, 512, 0, stream>>>(qb, kb, vt, mbits, ctxb);

    gemm_out32<<<dim3(64, 16), 256, 0, stream>>>(ctxb, Wt3, bo, Q, outp);

    layernorm1024<<<MROWS, 256, 0, stream>>>(outp, gam, bet, out);
}